// Round 15
// baseline (211.849 us; speedup 1.0000x reference)
//
#include <hip/hip_runtime.h>
#include <float.h>
#include <math.h>

#define TOKS 16384
#define HDIM 4096
#define NEXP 64
#define BM   64            // tokens per block tile
#define NTILE (TOKS / BM)  // 256
#define KS   4             // K-slices; kSlice = 1024 = 16 chunks of BK=64
#define NCHS 16            // chunks per slice
#define WPE  262144        // u16 elems per w bf16 plane (64*4096)

typedef __attribute__((ext_vector_type(8)))  short short8v;  // 8 bf16 = one A/B frag
typedef __attribute__((ext_vector_type(16))) float f32x16;   // C/D frag

// Exact 3-way bf16 split by truncation: v = s1+s2+s3+eps, eps <= 2^-24*|v|.
__device__ __forceinline__ void split3(float v, unsigned& b1, unsigned& b2, unsigned& b3) {
  unsigned xb = __float_as_uint(v);
  b1 = xb >> 16;
  float r = v - __uint_as_float(xb & 0xFFFF0000u);
  unsigned rb = __float_as_uint(r);
  b2 = rb >> 16;
  float r2 = r - __uint_as_float(rb & 0xFFFF0000u);
  b3 = __float_as_uint(r2) >> 16;
}
__device__ __forceinline__ void cvt2(float a, float b, unsigned& o1, unsigned& o2, unsigned& o3) {
  unsigned a1, a2, a3, c1, c2, c3;
  split3(a, a1, a2, a3);
  split3(b, c1, c2, c3);
  o1 = a1 | (c1 << 16); o2 = a2 | (c2 << 16); o3 = a3 | (c3 << 16);
}

// ---- pre-kernel: w [64][4096] f32 -> 3 bf16 planes [3][64][4096] (row-major) ----
__global__ __launch_bounds__(256)
void wsplit_kernel(const float* __restrict__ wgt, unsigned short* __restrict__ wsp) {
  const int gid  = blockIdx.x * 256 + threadIdx.x;   // 32768 threads x 8 elems
  const int base = gid * 8;
  const float4 f0 = *(const float4*)(wgt + base);
  const float4 f1 = *(const float4*)(wgt + base + 4);
  uint4 q1, q2, q3;
  cvt2(f0.x, f0.y, q1.x, q2.x, q3.x);
  cvt2(f0.z, f0.w, q1.y, q2.y, q3.y);
  cvt2(f1.x, f1.y, q1.z, q2.z, q3.z);
  cvt2(f1.z, f1.w, q1.w, q2.w, q3.w);
  *(uint4*)(wsp + base)            = q1;
  *(uint4*)(wsp + WPE + base)      = q2;
  *(uint4*)(wsp + 2 * WPE + base)  = q3;
}

__device__ __forceinline__ void gload_lds16(const float* g, void* l) {
  __builtin_amdgcn_global_load_lds((const __attribute__((address_space(1))) void*)g,
                                   (__attribute__((address_space(3))) void*)l, 16, 0, 0);
}

#define WAITVM8() do { asm volatile("s_waitcnt vmcnt(8)" ::: "memory"); \
                       __builtin_amdgcn_sched_barrier(0); } while (0)

// ---- stage 1: ZERO-BARRIER wave-private pipelines ----
// grid (256 tiles, KS=4). Block 256 thr = 4 fully independent waves
// (wm=wv>>1 tok-half, we=wv&1 exp-half); wave = 32tok x 32exp,
// mfma_f32_32x32x16_bf16, 6 MFMA/k16 via 3-way split, 5 acc chains.
// Each wave DMA-stages ITS OWN 32 A-rows x 64k fp32 chunk (8 KB) into
// wave-private LDS (2 bufs), granule-swizzled source (g -> row,q^(row&7)).
// Sync is per-wave only: DMA(c+2) is issued LAST each iter, so the 8
// newest vmem ops are always the newest DMA batch; vmcnt(8) + in-order
// retirement ==> chunk c landed. No s_barrier anywhere: waves drift,
// mutually hiding ds_read/MFMA-chain/HBM latency on each SIMD.
__global__ __launch_bounds__(256)
void router_mfma_kernel(const float* __restrict__ x,
                        const unsigned short* __restrict__ wsp,
                        float* __restrict__ part) {
  __shared__ __align__(16) unsigned char smem[65536];
  const int tid  = threadIdx.x;
  const int lane = tid & 63;
  const int wv   = tid >> 6;
  const int kt   = blockIdx.y;
  const int tokBase = blockIdx.x * BM;
  const int kStart  = kt * (HDIM / KS);

  const int wm = wv >> 1, we = wv & 1;
  const int r  = lane & 31, h2 = lane >> 5;
  const int r7 = r & 7;

  unsigned char* const mybuf = smem + wv * 16384;   // wave-private: 2 x 8 KB

  // DMA sources: 8 instr/chunk; instr j, lane l -> LDS granule G = j*64+l,
  // row = G>>4 (0..31), q = G&15, src granule q' = q ^ (row&7)  (involution)
  const int srow = lane >> 4;               // row within instr group
  const int sq   = lane & 15;
  const float* const xbase = x + (size_t)(tokBase + wm * 32) * HDIM + kStart;

  // compute-side B pointer (pre-split bf16 planes, L2-resident)
  const unsigned short* const bp = wsp + (size_t)(we * 32 + r) * HDIM + kStart + h2 * 8;

  f32x16 m0, m1, c0, c1, c2;
#pragma unroll
  for (int i = 0; i < 16; ++i) { m0[i] = 0.f; m1[i] = 0.f; c0[i] = 0.f; c1[i] = 0.f; c2[i] = 0.f; }

#define STAGE(buf, c) do { \
    unsigned char* lb_ = mybuf + (buf) * 8192; \
    _Pragma("unroll") \
    for (int j = 0; j < 8; ++j) { \
      const int row_ = j * 4 + srow; \
      const int qq_  = sq ^ (row_ & 7); \
      gload_lds16(xbase + (size_t)row_ * HDIM + (c) * 64 + qq_ * 4, lb_ + j * 1024); \
    } \
  } while (0)

#define MFMA(a, b, c) __builtin_amdgcn_mfma_f32_32x32x16_bf16((a), (b), (c), 0, 0, 0)

#define COMPUTE(buf, c) do { \
    const unsigned char* bb_ = mybuf + (buf) * 8192; \
    _Pragma("unroll") \
    for (int s = 0; s < 4; ++s) { \
      const int q0_ = s * 4 + h2 * 2; \
      const float4 xlo_ = *(const float4*)(bb_ + ((r * 16 + ( q0_      ^ r7)) << 4)); \
      const float4 xhi_ = *(const float4*)(bb_ + ((r * 16 + ((q0_ + 1) ^ r7)) << 4)); \
      uint4 q1_, q2_, q3_; \
      cvt2(xlo_.x, xlo_.y, q1_.x, q2_.x, q3_.x); \
      cvt2(xlo_.z, xlo_.w, q1_.y, q2_.y, q3_.y); \
      cvt2(xhi_.x, xhi_.y, q1_.z, q2_.z, q3_.z); \
      cvt2(xhi_.z, xhi_.w, q1_.w, q2_.w, q3_.w); \
      const short8v a1_ = __builtin_bit_cast(short8v, q1_); \
      const short8v a2_ = __builtin_bit_cast(short8v, q2_); \
      const short8v a3_ = __builtin_bit_cast(short8v, q3_); \
      const unsigned short* bq_ = bp + (c) * 64 + s * 16; \
      const short8v b1_ = *(const short8v*)(bq_); \
      const short8v b2_ = *(const short8v*)(bq_ + WPE); \
      const short8v b3_ = *(const short8v*)(bq_ + 2 * WPE); \
      if (s < 2) m0 = MFMA(a1_, b1_, m0); \
      else       m1 = MFMA(a1_, b1_, m1); \
      c0 = MFMA(a1_, b2_, c0); \
      c1 = MFMA(a2_, b1_, c1); \
      c2 = MFMA(a1_, b3_, c2); \
      c0 = MFMA(a2_, b2_, c0); \
      c1 = MFMA(a3_, b1_, c1); \
    } \
  } while (0)

  // ---- per-wave pipeline: prologue fills both buffers ----
  STAGE(0, 0);
  STAGE(1, 1);
#pragma unroll 1
  for (int c = 0; c < NCHS; ++c) {
    WAITVM8();                           // all but newest DMA batch done -> chunk c ready
    COMPUTE(c & 1, c);
    __builtin_amdgcn_sched_barrier(0);   // pin: ds_reads stay above the DMA reusing this buf
    if (c + 2 < NCHS) STAGE(c & 1, c + 2);  // issued LAST -> newest 8 vmem = this batch
  }

  // partial logits [kt][tile][64 tok][64 exp] (C/D: row=(reg&3)+8*(reg>>2)+4*h2)
  float* pp = part + ((size_t)kt * NTILE + blockIdx.x) * 4096;
#pragma unroll
  for (int reg = 0; reg < 16; ++reg) {
    const int rowf = (reg & 3) + 8 * (reg >> 2) + 4 * h2;
    pp[(wm * 32 + rowf) * 64 + we * 32 + r] =
        ((m0[reg] + m1[reg]) + (c0[reg] + c1[reg])) + c2[reg];
  }
}

// ---- stage 2: sum KS partials + bias, top-8 + softmax. 1024 blocks x 64 thr ----
__global__ __launch_bounds__(64)
void reduce_topk_kernel(const float* __restrict__ part,
                        const float* __restrict__ bias,
                        float* __restrict__ out) {
  __shared__ __align__(16) float fin[1024];       // 16 tokens x 64 experts
  const int lane = threadIdx.x;                   // 0..63
  const int g    = blockIdx.x;                    // tokens 16g..16g+15
  const int tile = g >> 2;
  const int rowBase = (g & 3) * 16;

  const int row = lane >> 2;
  const int e0  = (lane & 3) * 16;
  const size_t off0 = (size_t)tile * 4096 + (rowBase + row) * 64 + e0;
  float4 s0 = make_float4(0.f, 0.f, 0.f, 0.f), s1 = s0, s2 = s0, s3 = s0;
#pragma unroll
  for (int kt = 0; kt < KS; ++kt) {
    const float* p = part + (size_t)kt * (NTILE * 4096) + off0;
    const float4 q0 = *(const float4*)(p);
    const float4 q1 = *(const float4*)(p + 4);
    const float4 q2 = *(const float4*)(p + 8);
    const float4 q3 = *(const float4*)(p + 12);
    s0.x += q0.x; s0.y += q0.y; s0.z += q0.z; s0.w += q0.w;
    s1.x += q1.x; s1.y += q1.y; s1.z += q1.z; s1.w += q1.w;
    s2.x += q2.x; s2.y += q2.y; s2.z += q2.z; s2.w += q2.w;
    s3.x += q3.x; s3.y += q3.y; s3.z += q3.z; s3.w += q3.w;
  }
  *(float4*)(&fin[lane * 16])      = s0;
  *(float4*)(&fin[lane * 16 + 4])  = s1;
  *(float4*)(&fin[lane * 16 + 8])  = s2;
  *(float4*)(&fin[lane * 16 + 12]) = s3;
  __syncthreads();

  for (int tt = 0; tt < 16; ++tt) {
    float v = fin[tt * 64 + lane] + bias[lane];   // lane = expert id
    float myval = 0.f, m0 = 0.f;
    int myidx = 0;
#pragma unroll
    for (int k = 0; k < 8; ++k) {
      float bv = v;
      int   bi = lane;
#pragma unroll
      for (int off = 1; off < 64; off <<= 1) {    // argmax, min-index tiebreak
        const float ov = __shfl_xor(bv, off);
        const int   oi = __shfl_xor(bi, off);
        if (ov > bv || (ov == bv && oi < bi)) { bv = ov; bi = oi; }
      }
      if (k == 0) m0 = bv;
      if (lane == k) { myval = bv; myidx = bi; }
      if (lane == bi) v = -FLT_MAX;               // bi is wave-uniform
    }
    const float el = (lane < 8) ? expf(myval - m0) : 0.f;
    float ssum = el;
    ssum += __shfl_xor(ssum, 1);
    ssum += __shfl_xor(ssum, 2);
    ssum += __shfl_xor(ssum, 4);
    if (lane < 8) {
      const size_t tg = (size_t)g * 16 + tt;
      out[tg * 8 + lane] = el / ssum;                        // weights (f32)
      out[(size_t)TOKS * 8 + tg * 8 + lane] = (float)myidx;  // indices as f32
    }
  }
}

extern "C" void kernel_launch(void* const* d_in, const int* in_sizes, int n_in,
                              void* d_out, int out_size, void* d_ws, size_t ws_size,
                              hipStream_t stream) {
  const float* x    = (const float*)d_in[0];
  const float* wgt  = (const float*)d_in[1];
  const float* bias = (const float*)d_in[2];
  float* out  = (float*)d_out;
  float* part = (float*)d_ws;   // KS planes x 4 MiB, then 1.5 MiB w-planes

  unsigned short* wsp = (unsigned short*)((char*)d_ws + (size_t)KS * NTILE * 4096 * sizeof(float));

  hipLaunchKernelGGL(wsplit_kernel, dim3(NEXP * HDIM / (256 * 8)), dim3(256), 0, stream,
                     wgt, wsp);
  hipLaunchKernelGGL(router_mfma_kernel, dim3(NTILE, KS), dim3(256), 0, stream,
                     x, wsp, part);
  hipLaunchKernelGGL(reduce_topk_kernel, dim3(TOKS / 16), dim3(64), 0, stream,
                     part, bias, out);
}

// Round 16
// 173.024 us; speedup vs baseline: 1.2244x; 1.2244x over previous
//
#include <hip/hip_runtime.h>
#include <float.h>
#include <math.h>

#define TOKS 16384
#define HDIM 4096
#define NEXP 64
#define BM   64            // tokens per block tile
#define NTILE (TOKS / BM)  // 256
#define KS   8             // K-slices; kSlice = 512 = 16 chunks of BK=32
#define NCHS 16            // chunks per slice
#define BK   32
#define WPE  262144        // u16 elems per w bf16 plane (64*4096)

typedef __attribute__((ext_vector_type(8)))  short short8v;  // 8 bf16 = one A/B frag
typedef __attribute__((ext_vector_type(16))) float f32x16;   // C/D frag

// Exact 3-way bf16 split by truncation: v = s1+s2+s3+eps, eps <= 2^-24*|v|.
__device__ __forceinline__ void split3(float v, unsigned& b1, unsigned& b2, unsigned& b3) {
  unsigned xb = __float_as_uint(v);
  b1 = xb >> 16;
  float r = v - __uint_as_float(xb & 0xFFFF0000u);
  unsigned rb = __float_as_uint(r);
  b2 = rb >> 16;
  float r2 = r - __uint_as_float(rb & 0xFFFF0000u);
  b3 = __float_as_uint(r2) >> 16;
}
__device__ __forceinline__ void cvt2(float a, float b, unsigned& o1, unsigned& o2, unsigned& o3) {
  unsigned a1, a2, a3, c1, c2, c3;
  split3(a, a1, a2, a3);
  split3(b, c1, c2, c3);
  o1 = a1 | (c1 << 16); o2 = a2 | (c2 << 16); o3 = a3 | (c3 << 16);
}

// ---- pre-kernel: w [64][4096] f32 -> 3 bf16 planes [3][64][4096] (row-major) ----
__global__ __launch_bounds__(256)
void wsplit_kernel(const float* __restrict__ wgt, unsigned short* __restrict__ wsp) {
  const int gid  = blockIdx.x * 256 + threadIdx.x;   // 32768 threads x 8 elems
  const int base = gid * 8;
  const float4 f0 = *(const float4*)(wgt + base);
  const float4 f1 = *(const float4*)(wgt + base + 4);
  uint4 q1, q2, q3;
  cvt2(f0.x, f0.y, q1.x, q2.x, q3.x);
  cvt2(f0.z, f0.w, q1.y, q2.y, q3.y);
  cvt2(f1.x, f1.y, q1.z, q2.z, q3.z);
  cvt2(f1.z, f1.w, q1.w, q2.w, q3.w);
  *(uint4*)(wsp + base)            = q1;
  *(uint4*)(wsp + WPE + base)      = q2;
  *(uint4*)(wsp + 2 * WPE + base)  = q3;
}

__device__ __forceinline__ void gload_lds16(const void* g, void* l) {
  __builtin_amdgcn_global_load_lds((const __attribute__((address_space(1))) void*)g,
                                   (__attribute__((address_space(3))) void*)l, 16, 0, 0);
}

#define WAITVM(N) do { asm volatile("s_waitcnt vmcnt(" #N ")" ::: "memory"); \
                       __builtin_amdgcn_sched_barrier(0); } while (0)
#define RBAR()    do { __builtin_amdgcn_s_barrier(); \
                       __builtin_amdgcn_sched_barrier(0); } while (0)

// ---- stage 1: vmem-free inner loop ----
// R10-R15 post-mortem: per-s-step B global loads share vmcnt with the staging
// DMAs; the compiler's wait before each B-consuming MFMA drains ALL older
// in-flight DMAs (in-order counter) -> every "async" pipeline was depth-0.
// Fix: B staged into LDS by the same DMA batches as A; COMPUTE has ZERO vmem.
// Buf = A fp32 [64 tok][32 k] (8 KB, granule-swz q^=(row&7)) +
//       B bf16 3 planes [64 exp][32 k] (12 KB, q^=(row&3)) = 20 KB; 2 bufs.
// Per wave per chunk: 5 gload_lds (2 A + 3 B). One counted WAITVM(5)/chunk:
// chunk c+1 landed, chunk c+2 stays in flight across the whole next compute.
__global__ __launch_bounds__(256)
void router_mfma_kernel(const float* __restrict__ x,
                        const unsigned short* __restrict__ wsp,
                        float* __restrict__ part) {
  __shared__ __align__(16) unsigned char smem[40960];
  const int tid  = threadIdx.x;
  const int lane = tid & 63;
  const int wv   = tid >> 6;
  const int kt   = blockIdx.y;
  const int tokBase = blockIdx.x * BM;
  const int kStart  = kt * (HDIM / KS);

  // --- A staging (2 instr/wave): instr j covers rows wv*16+j*8+(l>>3), 8 granules/row
  const int arow = wv * 16 + (lane >> 3);           // + 8 for instr 1
  const int aq   = (lane & 7) ^ (lane >> 3);        // src granule (involution, row&7=l>>3)
  const float* const asrc0 = x + (size_t)(tokBase + arow) * HDIM + kStart + aq * 4;
  const float* const asrc1 = asrc0 + (size_t)8 * HDIM;
  // --- B staging (3 instr/wave): instr t = plane t, rows wv*16+(l>>2), 4 granules/row
  const int brow = wv * 16 + (lane >> 2);
  const int bq   = (lane & 3) ^ ((lane >> 2) & 3);
  const unsigned short* const bsrc0 = wsp +           (size_t)brow * HDIM + kStart + bq * 8;
  const unsigned short* const bsrc1 = bsrc0 + WPE;
  const unsigned short* const bsrc2 = bsrc0 + 2 * WPE;

  // compute mapping: wave (wm tok-half, we exp-half) = 32tok x 32exp
  const int wm = wv >> 1, we = wv & 1;
  const int r  = lane & 31, h2 = lane >> 5;
  const int rA = wm * 32 + r;     const int r7A = rA & 7;
  const int rB = we * 32 + r;     const int r3B = rB & 3;

  f32x16 m0, m1, c0, c1;
#pragma unroll
  for (int i = 0; i < 16; ++i) { m0[i] = 0.f; m1[i] = 0.f; c0[i] = 0.f; c1[i] = 0.f; }

#define STAGE(buf, c) do { \
    unsigned char* lb_ = smem + (buf) * 20480; \
    const int kc_ = (c) * BK; \
    gload_lds16(asrc0 + kc_, lb_ + wv * 2048); \
    gload_lds16(asrc1 + kc_, lb_ + wv * 2048 + 1024); \
    gload_lds16(bsrc0 + kc_, lb_ + 8192 + wv * 1024); \
    gload_lds16(bsrc1 + kc_, lb_ + 8192 + (wv + 4) * 1024); \
    gload_lds16(bsrc2 + kc_, lb_ + 8192 + (wv + 8) * 1024); \
  } while (0)

#define MFMA(a, b, c) __builtin_amdgcn_mfma_f32_32x32x16_bf16((a), (b), (c), 0, 0, 0)

  // 2 k16-steps per chunk; A & B from LDS only (5 ds_read + ~70 VALU + 7 MFMA per step)
#define COMPUTE(buf) do { \
    const unsigned char* ab_ = smem + (buf) * 20480; \
    const unsigned char* bb_ = ab_ + 8192; \
    _Pragma("unroll") \
    for (int s = 0; s < 2; ++s) { \
      const int qa_ = s * 4 + h2 * 2; \
      const float4 xlo_ = *(const float4*)(ab_ + rA * 128 + (( qa_      ^ r7A) << 4)); \
      const float4 xhi_ = *(const float4*)(ab_ + rA * 128 + (((qa_ + 1) ^ r7A) << 4)); \
      uint4 q1_, q2_, q3_; \
      cvt2(xlo_.x, xlo_.y, q1_.x, q2_.x, q3_.x); \
      cvt2(xlo_.z, xlo_.w, q1_.y, q2_.y, q3_.y); \
      cvt2(xhi_.x, xhi_.y, q1_.z, q2_.z, q3_.z); \
      cvt2(xhi_.z, xhi_.w, q1_.w, q2_.w, q3_.w); \
      const short8v a1_ = __builtin_bit_cast(short8v, q1_); \
      const short8v a2_ = __builtin_bit_cast(short8v, q2_); \
      const short8v a3_ = __builtin_bit_cast(short8v, q3_); \
      const int qb_ = ((s * 2 + h2) ^ r3B) << 4; \
      const short8v b1_ = *(const short8v*)(bb_ +        rB * 64 + qb_); \
      const short8v b2_ = *(const short8v*)(bb_ + 4096 + rB * 64 + qb_); \
      const short8v b3_ = *(const short8v*)(bb_ + 8192 + rB * 64 + qb_); \
      if (s == 0) m0 = MFMA(a1_, b1_, m0); \
      else        m1 = MFMA(a1_, b1_, m1); \
      c0 = MFMA(a1_, b2_, c0); \
      c1 = MFMA(a2_, b1_, c1); \
      c0 = MFMA(a1_, b3_, c0); \
      c1 = MFMA(a2_, b2_, c1); \
      c0 = MFMA(a3_, b1_, c0); \
    } \
  } while (0)

  // ---- pipeline: 2 bufs, counted vmcnt, depth preserved across compute ----
  STAGE(0, 0);
  STAGE(1, 1);
  WAITVM(5);            // all but newest 5 done -> chunk 0 landed
  RBAR();
#pragma unroll 1
  for (int c = 0; c < NCHS; ++c) {
    COMPUTE(c & 1);
    RBAR();                              // all waves done reading buf c&1
    if (c + 2 < NCHS) {
      STAGE(c & 1, c + 2);               // 5 DMA, issued last
      WAITVM(5);                         // chunk c+1 landed; c+2 stays in flight
      RBAR();
    } else if (c + 1 < NCHS) {
      WAITVM(0);                         // final chunk's DMAs
      RBAR();
    }
  }

  // partial logits [kt][tile][64 tok][64 exp] (C/D: row=(reg&3)+8*(reg>>2)+4*h2)
  float* pp = part + ((size_t)kt * NTILE + blockIdx.x) * 4096;
#pragma unroll
  for (int reg = 0; reg < 16; ++reg) {
    const int rowf = (reg & 3) + 8 * (reg >> 2) + 4 * h2;
    pp[(wm * 32 + rowf) * 64 + we * 32 + r] = (m0[reg] + m1[reg]) + (c0[reg] + c1[reg]);
  }
}

// ---- stage 2: sum KS partials + bias, top-8 + softmax. 1024 blocks x 64 thr ----
__global__ __launch_bounds__(64)
void reduce_topk_kernel(const float* __restrict__ part,
                        const float* __restrict__ bias,
                        float* __restrict__ out) {
  __shared__ __align__(16) float fin[1024];       // 16 tokens x 64 experts
  const int lane = threadIdx.x;                   // 0..63
  const int g    = blockIdx.x;                    // tokens 16g..16g+15
  const int tile = g >> 2;
  const int rowBase = (g & 3) * 16;

  const int row = lane >> 2;
  const int e0  = (lane & 3) * 16;
  const size_t off0 = (size_t)tile * 4096 + (rowBase + row) * 64 + e0;
  float4 s0 = make_float4(0.f, 0.f, 0.f, 0.f), s1 = s0, s2 = s0, s3 = s0;
#pragma unroll
  for (int kt = 0; kt < KS; ++kt) {
    const float* p = part + (size_t)kt * (NTILE * 4096) + off0;
    const float4 q0 = *(const float4*)(p);
    const float4 q1 = *(const float4*)(p + 4);
    const float4 q2 = *(const float4*)(p + 8);
    const float4 q3 = *(const float4*)(p + 12);
    s0.x += q0.x; s0.y += q0.y; s0.z += q0.z; s0.w += q0.w;
    s1.x += q1.x; s1.y += q1.y; s1.z += q1.z; s1.w += q1.w;
    s2.x += q2.x; s2.y += q2.y; s2.z += q2.z; s2.w += q2.w;
    s3.x += q3.x; s3.y += q3.y; s3.z += q3.z; s3.w += q3.w;
  }
  *(float4*)(&fin[lane * 16])      = s0;
  *(float4*)(&fin[lane * 16 + 4])  = s1;
  *(float4*)(&fin[lane * 16 + 8])  = s2;
  *(float4*)(&fin[lane * 16 + 12]) = s3;
  __syncthreads();

  for (int tt = 0; tt < 16; ++tt) {
    float v = fin[tt * 64 + lane] + bias[lane];   // lane = expert id
    float myval = 0.f, m0 = 0.f;
    int myidx = 0;
#pragma unroll
    for (int k = 0; k < 8; ++k) {
      float bv = v;
      int   bi = lane;
#pragma unroll
      for (int off = 1; off < 64; off <<= 1) {    // argmax, min-index tiebreak
        const float ov = __shfl_xor(bv, off);
        const int   oi = __shfl_xor(bi, off);
        if (ov > bv || (ov == bv && oi < bi)) { bv = ov; bi = oi; }
      }
      if (k == 0) m0 = bv;
      if (lane == k) { myval = bv; myidx = bi; }
      if (lane == bi) v = -FLT_MAX;               // bi is wave-uniform
    }
    const float el = (lane < 8) ? expf(myval - m0) : 0.f;
    float ssum = el;
    ssum += __shfl_xor(ssum, 1);
    ssum += __shfl_xor(ssum, 2);
    ssum += __shfl_xor(ssum, 4);
    if (lane < 8) {
      const size_t tg = (size_t)g * 16 + tt;
      out[tg * 8 + lane] = el / ssum;                        // weights (f32)
      out[(size_t)TOKS * 8 + tg * 8 + lane] = (float)myidx;  // indices as f32
    }
  }
}

extern "C" void kernel_launch(void* const* d_in, const int* in_sizes, int n_in,
                              void* d_out, int out_size, void* d_ws, size_t ws_size,
                              hipStream_t stream) {
  const float* x    = (const float*)d_in[0];
  const float* wgt  = (const float*)d_in[1];
  const float* bias = (const float*)d_in[2];
  float* out  = (float*)d_out;
  float* part = (float*)d_ws;   // KS planes x 4 MiB, then 1.5 MiB w-planes

  unsigned short* wsp = (unsigned short*)((char*)d_ws + (size_t)KS * NTILE * 4096 * sizeof(float));

  hipLaunchKernelGGL(wsplit_kernel, dim3(NEXP * HDIM / (256 * 8)), dim3(256), 0, stream,
                     wgt, wsp);
  hipLaunchKernelGGL(router_mfma_kernel, dim3(NTILE, KS), dim3(256), 0, stream,
                     x, wsp, part);
  hipLaunchKernelGGL(reduce_topk_kernel, dim3(TOKS / 16), dim3(64), 0, stream,
                     part, bias, out);
}